// Round 3
// baseline (845.130 us; speedup 1.0000x reference)
//
#include <hip/hip_runtime.h>

// select_decoder_vectors: out[i,:] = values[i] * W_D[layer_idx[i], feat_idx[i], :]
// W_D (12, 16384, 768) f32, nnz = 131072, d_model = 768.
//
// v3: persistent waves + software-pipelined gather.
// Prior rounds (1 wave = 1-2 rows, then exit) sat at ~835 us ~= 0.96 TB/s --
// 6.5x off the 6.2 TB/s the harness's own fills achieve. Diagnosis:
// latency-bound. Each short-lived wave serialized two HBM round trips
// (index load -> dependent row load) for only 12 KB of traffic.
// Now each wave owns 16 contiguous rows (layer-sorted order preserved for
// L3 locality; ~48 MB per-layer working set << 256 MB L3). Per group of 4
// rows: issue 12 float4 row-loads, then prefetch the NEXT group's indices
// (1x float4 + 2x int4, hidden under the row-load latency), then
// scale + nontemporal-store. Waves never exit; index latency amortized.

#define D_MODEL 768
#define D_SAE   16384
#define WAVES_PER_BLOCK 4
#define GROUP 4
#define GROUPS_PER_WAVE 4
#define ROWS_PER_WAVE (GROUP * GROUPS_PER_WAVE)          // 16
#define ROWS_PER_BLOCK (ROWS_PER_WAVE * WAVES_PER_BLOCK) // 64

typedef float f32x4 __attribute__((ext_vector_type(4)));
typedef int   i32x4 __attribute__((ext_vector_type(4)));

__global__ __launch_bounds__(256) void gather_scale_kernel(
    const float* __restrict__ W_D,
    const float* __restrict__ values,
    const int*   __restrict__ layer_idx,
    const int*   __restrict__ feat_idx,
    float*       __restrict__ out,
    int nnz)
{
    const int wave = threadIdx.x >> 6;
    const int lane = threadIdx.x & 63;
    const long long gwave = (long long)blockIdx.x * WAVES_PER_BLOCK + wave;
    const long long base  = gwave * ROWS_PER_WAVE;
    if (base >= nnz) return;

    if (base + ROWS_PER_WAVE <= nnz) {
        // ---- fast path: full 16-row chunk, vectorized index loads ----
        // prologue: indices for group 0 (base is a multiple of 16 -> aligned)
        f32x4 v  = *(const f32x4*)(values    + base);
        i32x4 li = *(const i32x4*)(layer_idx + base);
        i32x4 fi = *(const i32x4*)(feat_idx  + base);

        #pragma unroll
        for (int g = 0; g < GROUPS_PER_WAVE; ++g) {
            const long long r0 = base + (long long)g * GROUP;

            const f32x4* __restrict__ s0 =
                (const f32x4*)(W_D + ((long long)li.x * D_SAE + fi.x) * D_MODEL);
            const f32x4* __restrict__ s1 =
                (const f32x4*)(W_D + ((long long)li.y * D_SAE + fi.y) * D_MODEL);
            const f32x4* __restrict__ s2 =
                (const f32x4*)(W_D + ((long long)li.z * D_SAE + fi.z) * D_MODEL);
            const f32x4* __restrict__ s3 =
                (const f32x4*)(W_D + ((long long)li.w * D_SAE + fi.w) * D_MODEL);

            // issue all 12 row loads (12 KB/wave in flight)
            f32x4 a0[3], a1[3], a2[3], a3[3];
            #pragma unroll
            for (int i = 0; i < 3; ++i) a0[i] = s0[lane + 64 * i];
            #pragma unroll
            for (int i = 0; i < 3; ++i) a1[i] = s1[lane + 64 * i];
            #pragma unroll
            for (int i = 0; i < 3; ++i) a2[i] = s2[lane + 64 * i];
            #pragma unroll
            for (int i = 0; i < 3; ++i) a3[i] = s3[lane + 64 * i];

            // prefetch next group's indices under the row-load latency
            f32x4 vn = v; i32x4 lin = li, fin = fi;
            if (g + 1 < GROUPS_PER_WAVE) {
                const long long nb = r0 + GROUP;
                vn  = *(const f32x4*)(values    + nb);
                lin = *(const i32x4*)(layer_idx + nb);
                fin = *(const i32x4*)(feat_idx  + nb);
            }

            // scale + nontemporal store (write-once output; keep L2/L3 for W_D)
            f32x4* __restrict__ d0 = (f32x4*)(out + r0 * D_MODEL);
            f32x4* __restrict__ d1 = d0 + (D_MODEL / 4);
            f32x4* __restrict__ d2 = d1 + (D_MODEL / 4);
            f32x4* __restrict__ d3 = d2 + (D_MODEL / 4);
            #pragma unroll
            for (int i = 0; i < 3; ++i)
                __builtin_nontemporal_store(a0[i] * v.x, &d0[lane + 64 * i]);
            #pragma unroll
            for (int i = 0; i < 3; ++i)
                __builtin_nontemporal_store(a1[i] * v.y, &d1[lane + 64 * i]);
            #pragma unroll
            for (int i = 0; i < 3; ++i)
                __builtin_nontemporal_store(a2[i] * v.z, &d2[lane + 64 * i]);
            #pragma unroll
            for (int i = 0; i < 3; ++i)
                __builtin_nontemporal_store(a3[i] * v.w, &d3[lane + 64 * i]);

            v = vn; li = lin; fi = fin;
        }
    } else {
        // ---- tail path: per-row scalar indices (nnz not multiple of 16) ----
        for (long long r = base; r < nnz; ++r) {
            const float vv = values[r];
            const long long sr = (long long)layer_idx[r] * D_SAE + feat_idx[r];
            const f32x4* __restrict__ src = (const f32x4*)(W_D + sr * D_MODEL);
            f32x4* __restrict__ dst = (f32x4*)(out + r * D_MODEL);
            #pragma unroll
            for (int i = 0; i < 3; ++i)
                __builtin_nontemporal_store(src[lane + 64 * i] * vv,
                                            &dst[lane + 64 * i]);
        }
    }
}

extern "C" void kernel_launch(void* const* d_in, const int* in_sizes, int n_in,
                              void* d_out, int out_size, void* d_ws, size_t ws_size,
                              hipStream_t stream) {
    const float* W_D       = (const float*)d_in[0];
    const float* values    = (const float*)d_in[1];
    const int*   layer_idx = (const int*)d_in[2];
    // d_in[3] = pos_idx (unused by reference)
    const int*   feat_idx  = (const int*)d_in[4];
    float*       out       = (float*)d_out;

    const int nnz = in_sizes[1];  // 131072
    const int blocks = (nnz + ROWS_PER_BLOCK - 1) / ROWS_PER_BLOCK;  // 2048
    gather_scale_kernel<<<blocks, 256, 0, stream>>>(W_D, values, layer_idx, feat_idx, out, nnz);
}